// Round 11
// baseline (1064.367 us; speedup 1.0000x reference)
//
#include <hip/hip_runtime.h>

// ---------------------------------------------------------------------------
// DecoderLayer forward: B=4, S=2048, D=1024, F=4096, single-head causal attn.
// Round 11: staging switched from global_load_lds (measured ~17 B/cyc/CU,
// the r3-r10 plateau) to buffer_load->VGPR->ds_write (L2 ubench proves the
// regular-load TA path sustains ~56 B/cyc/CU). Pipeline per iter:
//   barrier -> ds_write(it+1) [regs from load issued a full iter ago]
//           -> global_load(it+2) into regs -> compute(it).
// dbuf LDS, 1 barrier/iter, XOR-swizzle (0 conflicts both sides), r10's
// super-tile remap kept. Scores GEMM now outputs bf16 (halves sc traffic).
// ---------------------------------------------------------------------------

typedef __attribute__((ext_vector_type(8))) short short8;   // 8 x bf16 (4 VGPR)
typedef __attribute__((ext_vector_type(4))) float f32x4;    // MFMA C/D

#define DMODEL 1024
#define DFF    4096
#define NB     4
#define SEQ    2048
#define NROWS  (NB * SEQ)   // 8192
#define QKVN   (3 * DMODEL) // 3072

__device__ __forceinline__ unsigned short f2bf(float f) {
  union { float f; unsigned u; } v; v.f = f;
  unsigned r = v.u + 0x7FFFu + ((v.u >> 16) & 1u);  // round-to-nearest-even
  return (unsigned short)(r >> 16);
}
__device__ __forceinline__ float bf2f(unsigned short h) {
  union { unsigned u; float f; } v; v.u = ((unsigned)h) << 16;
  return v.f;
}

// ---- fp32 -> bf16 convert, all 6 weight tensors in one launch ----
__global__ __launch_bounds__(256) void cvt_bf16_all(
    const float* __restrict__ s0, const float* __restrict__ s1,
    const float* __restrict__ s2, const float* __restrict__ s3,
    const float* __restrict__ s4, const float* __restrict__ s5,
    unsigned short* __restrict__ d0, unsigned short* __restrict__ d1,
    unsigned short* __restrict__ d2, unsigned short* __restrict__ d3,
    unsigned short* __restrict__ d4, unsigned short* __restrict__ d5,
    int n_small, int n_big) {
  const int z = blockIdx.y;
  const float* src; unsigned short* dst; int n4;
  switch (z) {
    case 0: src = s0; dst = d0; n4 = n_small; break;
    case 1: src = s1; dst = d1; n4 = n_small; break;
    case 2: src = s2; dst = d2; n4 = n_small; break;
    case 3: src = s3; dst = d3; n4 = n_small; break;
    case 4: src = s4; dst = d4; n4 = n_big;   break;
    default: src = s5; dst = d5; n4 = n_big;  break;
  }
  int i = blockIdx.x * 256 + threadIdx.x;
  if (i >= n4) return;
  float4 v = reinterpret_cast<const float4*>(src)[i];
  ushort4 o;
  o.x = f2bf(v.x); o.y = f2bf(v.y); o.z = f2bf(v.z); o.w = f2bf(v.w);
  reinterpret_cast<ushort4*>(dst)[i] = o;
}

// ---- LayerNorm over D=1024, one 256-thread block per row, bf16 out ----
__global__ __launch_bounds__(256) void ln_bf16(const float* __restrict__ x,
                                               const float* __restrict__ g,
                                               const float* __restrict__ b,
                                               unsigned short* __restrict__ out) {
  int row = blockIdx.x;
  int t = threadIdx.x;
  const float* xr = x + (size_t)row * DMODEL;
  float4 v = reinterpret_cast<const float4*>(xr)[t];
  float s  = v.x + v.y + v.z + v.w;
  float s2 = v.x*v.x + v.y*v.y + v.z*v.z + v.w*v.w;
  #pragma unroll
  for (int off = 32; off > 0; off >>= 1) {
    s  += __shfl_down(s, off);
    s2 += __shfl_down(s2, off);
  }
  __shared__ float rs[4], rs2[4], stats[2];
  int lane = t & 63, wave = t >> 6;
  if (lane == 0) { rs[wave] = s; rs2[wave] = s2; }
  __syncthreads();
  if (t == 0) {
    float ts  = rs[0] + rs[1] + rs[2] + rs[3];
    float ts2 = rs2[0] + rs2[1] + rs2[2] + rs2[3];
    float mu = ts / DMODEL;
    stats[0] = mu;
    stats[1] = rsqrtf(ts2 / DMODEL - mu * mu + 1e-5f);
  }
  __syncthreads();
  float mu = stats[0], rstd = stats[1];
  float4 gg = reinterpret_cast<const float4*>(g)[t];
  float4 bb = reinterpret_cast<const float4*>(b)[t];
  ushort4 o;
  o.x = f2bf((v.x - mu) * rstd * gg.x + bb.x);
  o.y = f2bf((v.y - mu) * rstd * gg.y + bb.y);
  o.z = f2bf((v.z - mu) * rstd * gg.z + bb.z);
  o.w = f2bf((v.w - mu) * rstd * gg.w + bb.w);
  reinterpret_cast<ushort4*>(out + (size_t)row * DMODEL)[t] = o;
}

// ---- bf16 tile transpose: in [R][C] (row stride ldin) -> out [C][R] ----
__global__ __launch_bounds__(256) void transpose_bf16(const unsigned short* __restrict__ in,
                                                      unsigned short* __restrict__ out,
                                                      int R, int C, int ldin,
                                                      size_t sIn, size_t sOut) {
  __shared__ unsigned short tile[32][33];
  in  += (size_t)blockIdx.z * sIn;
  out += (size_t)blockIdx.z * sOut;
  int c0 = blockIdx.x * 32, r0 = blockIdx.y * 32;
  int tx = threadIdx.x & 31, ty = threadIdx.x >> 5;  // 32 x 8
  #pragma unroll
  for (int i = 0; i < 4; ++i)
    tile[ty + i * 8][tx] = in[(size_t)(r0 + ty + i * 8) * ldin + c0 + tx];
  __syncthreads();
  #pragma unroll
  for (int i = 0; i < 4; ++i)
    out[(size_t)(c0 + ty + i * 8) * R + r0 + tx] = tile[tx][ty + i * 8];
}

// ---- causal row softmax: bf16 scores -> bf16 probs (zeros above diagonal) ----
__global__ __launch_bounds__(256) void softmax_causal(const unsigned short* __restrict__ Sc,
                                                      unsigned short* __restrict__ P) {
  const int q = blockIdx.x, b = blockIdx.y;
  const unsigned short* srow = Sc + ((size_t)b * SEQ + q) * SEQ;
  unsigned short* prow = P + ((size_t)b * SEQ + q) * SEQ;
  const int L = q + 1;
  const int t = threadIdx.x;
  __shared__ float red[4];
  __shared__ float bc;

  float mx = -1e30f;
  for (int i = t; i < L; i += 256) mx = fmaxf(mx, bf2f(srow[i]));
  #pragma unroll
  for (int off = 32; off > 0; off >>= 1) mx = fmaxf(mx, __shfl_down(mx, off));
  if ((t & 63) == 0) red[t >> 6] = mx;
  __syncthreads();
  if (t == 0) bc = fmaxf(fmaxf(red[0], red[1]), fmaxf(red[2], red[3]));
  __syncthreads();
  mx = bc;

  float sum = 0.f;
  for (int i = t; i < L; i += 256) sum += __expf(bf2f(srow[i]) - mx);
  #pragma unroll
  for (int off = 32; off > 0; off >>= 1) sum += __shfl_down(sum, off);
  __syncthreads();            // red reuse guard
  if ((t & 63) == 0) red[t >> 6] = sum;
  __syncthreads();
  if (t == 0) bc = 1.0f / (red[0] + red[1] + red[2] + red[3]);
  __syncthreads();
  float inv = bc;

  for (int i = t; i < SEQ; i += 256) {
    float p = (i < L) ? __expf(bf2f(srow[i]) - mx) * inv : 0.f;
    prow[i] = f2bf(p);
  }
}

// ---------------------------------------------------------------------------
// bf16 MFMA GEMM:  C[M,N] = A[M,K] * B[N,K]^T   (both K-contiguous)
// 128x128 tile, 4 waves (2x2), 4x4 of 16x16x32 MFMA, BK=64, dbuf LDS,
// ONE barrier/iter. Staging = buffer_load -> VGPR -> ds_write:
//   barrier; ds_write(it+1) [vmcnt satisfied: loads issued a full iter ago];
//   global_load(it+2) -> regs; compute(it).
// XOR-swizzle fetch (lane (srow,s) loads col-group s^srow) -> ds_write and
// fragment ds_read_b128 both lane-sequential = conflict-free.
// Super-tile remap (8x8) kept from r10. Epilogue fuses scale/bias/relu/resid.
// ---------------------------------------------------------------------------
template<bool OUT_F32, bool ADD_BIAS, bool RELU, bool ADD_RESID,
         bool CAUSAL_SKIP, bool CAUSAL_KLIM, bool SCALE>
__global__ __launch_bounds__(256) void gemm_bt(
    const unsigned short* __restrict__ A, size_t sA,
    const unsigned short* __restrict__ B, size_t sB,
    void* __restrict__ Cv, size_t sC,
    const float* __restrict__ bias,
    const float* __restrict__ resid, size_t sR,
    int K, int lda, int ldb, int ldc, float scale) {
  // ---- super-tile remap: 64 consecutive linear ids = 8 m-blocks x 8 n-blocks
  const int GX = gridDim.x;                    // m-blocks (multiple of 8)
  const int linear = blockIdx.y * GX + blockIdx.x;
  const int tileId = linear >> 6;
  const int within = linear & 63;
  const int mGroups = GX >> 3;
  const int m_blk = (tileId % mGroups) * 8 + (within & 7);
  const int n_blk = (tileId / mGroups) * 8 + (within >> 3);
  const int m0 = m_blk * 128;
  const int n0 = n_blk * 128;
  if (CAUSAL_SKIP && n0 > m0 + 127) return;  // block fully masked
  const int bz = blockIdx.z;
  A += (size_t)bz * sA;
  B += (size_t)bz * sB;

  __shared__ unsigned short As[2][128 * 64];   // 2 x 16 KB, XOR-swizzled
  __shared__ unsigned short Bs[2][128 * 64];

  const int t = threadIdx.x;
  const int lane = t & 63;
  const int wave = t >> 6;
  const int wm = (wave >> 1) * 64;
  const int wn = (wave & 1) * 64;
  const int lr = lane & 15;
  const int lq = lane >> 4;

  const int srow = lane >> 3;                  // 0..7
  const int pcol = ((lane & 7) ^ srow) * 8;    // XOR-swizzled fetch col

  f32x4 acc[4][4] = {};

  const int kEnd  = CAUSAL_KLIM ? min(K, m0 + 128) : K;
  const int nIter = kEnd >> 6;                 // BK = 64 (nIter >= 2 always here)

  float4 rA[4], rB[4];                         // staging registers (32 VGPR)

  auto load = [&](int kt) {
    #pragma unroll
    for (int i = 0; i < 4; ++i) {
      const int c = wave * 4 + i;              // chunk 0..15
      const int row = c * 8 + srow;
      rA[i] = *reinterpret_cast<const float4*>(&A[(size_t)(m0 + row) * lda + kt + pcol]);
      rB[i] = *reinterpret_cast<const float4*>(&B[(size_t)(n0 + row) * ldb + kt + pcol]);
    }
  };
  auto store = [&](int buf) {
    #pragma unroll
    for (int i = 0; i < 4; ++i) {
      const int c = wave * 4 + i;
      *reinterpret_cast<float4*>(&As[buf][c * 512 + lane * 8]) = rA[i];
      *reinterpret_cast<float4*>(&Bs[buf][c * 512 + lane * 8]) = rB[i];
    }
  };

  // prologue: tile 0 through regs into buf0 (one-time vmcnt stall), prefetch 1
  load(0);
  store(0);
  if (nIter > 1) load(64);

  for (int it = 0; it < nIter; ++it) {
    __syncthreads();   // buf[it&1] ready (ds_writes drained); other buf free
    if (it + 1 < nIter) store((it + 1) & 1);   // regs from a full iter ago
    if (it + 2 < nIter) load((it + 2) << 6);   // latency hidden by compute
    const unsigned short* Ab = As[it & 1];
    const unsigned short* Bb = Bs[it & 1];
    #pragma unroll
    for (int kk = 0; kk < 2; ++kk) {
      short8 af[4], bfr[4];
      #pragma unroll
      for (int i = 0; i < 4; ++i) {
        const int r = wm + i * 16 + lr;
        af[i] = *reinterpret_cast<const short8*>(
            &Ab[r * 64 + (((kk * 4 + lq) ^ (r & 7)) * 8)]);
      }
      #pragma unroll
      for (int j = 0; j < 4; ++j) {
        const int r = wn + j * 16 + lr;
        bfr[j] = *reinterpret_cast<const short8*>(
            &Bb[r * 64 + (((kk * 4 + lq) ^ (r & 7)) * 8)]);
      }
      #pragma unroll
      for (int i = 0; i < 4; ++i)
        #pragma unroll
        for (int j = 0; j < 4; ++j)
          acc[i][j] = __builtin_amdgcn_mfma_f32_16x16x32_bf16(af[i], bfr[j], acc[i][j], 0, 0, 0);
    }
  }

  float* Cf = (float*)Cv + (size_t)bz * sC;
  unsigned short* Ch = (unsigned short*)Cv + (size_t)bz * sC;
  const float* rr = ADD_RESID ? (resid + (size_t)bz * sR) : nullptr;
  #pragma unroll
  for (int i = 0; i < 4; ++i) {
    #pragma unroll
    for (int j = 0; j < 4; ++j) {
      #pragma unroll
      for (int r = 0; r < 4; ++r) {
        // C/D layout (verified m89/m91): col = lane&15, row = (lane>>4)*4 + reg
        int row = m0 + wm + i * 16 + lq * 4 + r;
        int col = n0 + wn + j * 16 + lr;
        float v = acc[i][j][r];
        if (SCALE)     v *= scale;
        if (ADD_BIAS)  v += bias[col];
        if (RELU)      v = fmaxf(v, 0.0f);
        if (ADD_RESID) v += rr[(size_t)row * ldc + col];
        if (OUT_F32) Cf[(size_t)row * ldc + col] = v;
        else         Ch[(size_t)row * ldc + col] = f2bf(v);
      }
    }
  }
}

// ---------------------------------------------------------------------------
extern "C" void kernel_launch(void* const* d_in, const int* in_sizes, int n_in,
                              void* d_out, int out_size, void* d_ws, size_t ws_size,
                              hipStream_t stream) {
  const float* x    = (const float*)d_in[0];
  const float* Wq   = (const float*)d_in[1];
  const float* Wk   = (const float*)d_in[2];
  const float* Wv   = (const float*)d_in[3];
  const float* Wo   = (const float*)d_in[4];
  const float* fc1w = (const float*)d_in[5];
  const float* fc1b = (const float*)d_in[6];
  const float* fc2w = (const float*)d_in[7];
  const float* fc2b = (const float*)d_in[8];
  const float* ln1g = (const float*)d_in[9];
  const float* ln1b = (const float*)d_in[10];
  const float* ln2g = (const float*)d_in[11];
  const float* ln2b = (const float*)d_in[12];
  float* out = (float*)d_out;

  // workspace carve-up with liveness aliasing
  char* w = (char*)d_ws;
  auto alloc = [&](size_t bytes) {
    char* p = w;
    w += (bytes + 255) & ~(size_t)255;
    return p;
  };
  typedef unsigned short u16;
  u16* wqkv_b = (u16*)alloc((size_t)QKVN * DMODEL * 2);   // stacked Q|K|V
  u16* wq_b   = wqkv_b;
  u16* wk_b   = wqkv_b + (size_t)DMODEL * DMODEL;
  u16* wv_b   = wqkv_b + (size_t)2 * DMODEL * DMODEL;
  u16* wo_b   = (u16*)alloc((size_t)DMODEL * DMODEL * 2);
  u16* fc1w_b = (u16*)alloc((size_t)DFF * DMODEL * 2);
  u16* fc2w_b = (u16*)alloc((size_t)DMODEL * DFF * 2);
  u16* xn     = (u16*)alloc((size_t)NROWS * DMODEL * 2);
  u16* qkv    = (u16*)alloc((size_t)NROWS * QKVN * 2);    // 48 MB
  u16* vt     = (u16*)alloc((size_t)NROWS * DMODEL * 2);
  u16* ctx    = (u16*)alloc((size_t)NROWS * DMODEL * 2);
  u16* xn2    = (u16*)alloc((size_t)NROWS * DMODEL * 2);
  // Region A (64 MB): sc_h (bf16 scores, steps 5-6) aliased with hbuf (10-11)
  char* regA  = (char*)alloc((size_t)NB * SEQ * SEQ * 4);
  u16*   sc_h = (u16*)regA;
  u16*   hbuf = (u16*)regA;
  // Region B (32 MB): Pbuf (steps 6-7) aliased with x1 (steps 8-11)
  char* regB  = (char*)alloc((size_t)NB * SEQ * SEQ * 2);
  u16*   Pbuf = (u16*)regB;
  float* x1   = (float*)regB;

  // 1. weights -> bf16 (single launch; z selects tensor)
  {
    int n_small = DMODEL * DMODEL / 4;
    int n_big   = DFF * DMODEL / 4;
    dim3 g((n_big + 255) / 256, 6);
    cvt_bf16_all<<<g, 256, 0, stream>>>(Wq, Wk, Wv, Wo, fc1w, fc2w,
                                        wq_b, wk_b, wv_b, wo_b, fc1w_b, fc2w_b,
                                        n_small, n_big);
  }

  // 2. LN1
  ln_bf16<<<dim3(NROWS), 256, 0, stream>>>(x, ln1g, ln1b, xn);

  // 3. merged QKV projection: [8192,1024] x [3072,1024]^T -> qkv [8192,3072]
  {
    dim3 g(NROWS / 128, QKVN / 128, 1);
    gemm_bt<false,false,false,false,false,false,false><<<g, 256, 0, stream>>>(
        xn, 0, wqkv_b, 0, qkv, 0, nullptr, nullptr, 0,
        DMODEL, DMODEL, DMODEL, QKVN, 1.f);
  }
  const u16* qb = qkv;                 // lda = QKVN
  const u16* kb = qkv + DMODEL;
  const u16* vb = qkv + 2 * DMODEL;

  // 4. V^T per batch: [2048,1024] (stride 3072) -> [1024,2048]
  transpose_bf16<<<dim3(DMODEL / 32, SEQ / 32, NB), 256, 0, stream>>>(
      vb, vt, SEQ, DMODEL, QKVN, (size_t)SEQ * QKVN, (size_t)DMODEL * SEQ);

  // 5. scores = Q K^T / sqrt(D), bf16 out, skip fully-masked blocks
  {
    dim3 g(SEQ / 128, SEQ / 128, NB);
    gemm_bt<false,false,false,false,true,false,true><<<g, 256, 0, stream>>>(
        qb, (size_t)SEQ * QKVN, kb, (size_t)SEQ * QKVN, sc_h, (size_t)SEQ * SEQ,
        nullptr, nullptr, 0, DMODEL, QKVN, QKVN, SEQ, 0.03125f /*1/sqrt(1024)*/);
  }

  // 6. causal softmax (bf16 in) -> bf16 probs (zeros above diagonal)
  softmax_causal<<<dim3(SEQ, NB), 256, 0, stream>>>(sc_h, Pbuf);

  // 7. ctx = P V  (K-reduction bounded by causality)
  {
    dim3 g(SEQ / 128, DMODEL / 128, NB);
    gemm_bt<false,false,false,false,false,true,false><<<g, 256, 0, stream>>>(
        Pbuf, (size_t)SEQ * SEQ, vt, (size_t)DMODEL * SEQ, ctx, (size_t)SEQ * DMODEL,
        nullptr, nullptr, 0, SEQ, SEQ, SEQ, DMODEL, 1.f);
  }

  // 8. x1 = x + ctx Wo^T  (fp32)  -- x1 aliases Pbuf (dead after step 7)
  {
    dim3 g(NROWS / 128, DMODEL / 128, 1);
    gemm_bt<true,false,false,true,false,false,false><<<g, 256, 0, stream>>>(
        ctx, 0, wo_b, 0, x1, 0, nullptr, x, 0, DMODEL, DMODEL, DMODEL, DMODEL, 1.f);
  }

  // 9. LN2
  ln_bf16<<<dim3(NROWS), 256, 0, stream>>>(x1, ln2g, ln2b, xn2);

  // 10. h = relu(xn2 fc1_w^T + fc1_b)  bf16 [8192,4096] -- hbuf aliases sc_h
  {
    dim3 g(NROWS / 128, DFF / 128, 1);
    gemm_bt<false,true,true,false,false,false,false><<<g, 256, 0, stream>>>(
        xn2, 0, fc1w_b, 0, hbuf, 0, fc1b, nullptr, 0, DMODEL, DMODEL, DMODEL, DFF, 1.f);
  }

  // 11. out = x1 + h fc2_w^T + fc2_b  (fp32)
  {
    dim3 g(NROWS / 128, DMODEL / 128, 1);
    gemm_bt<true,true,false,true,false,false,false><<<g, 256, 0, stream>>>(
        hbuf, 0, fc2w_b, 0, out, 0, fc2b, x1, 0, DFF, DFF, DFF, DMODEL, 1.f);
  }
}

// Round 12
// 519.279 us; speedup vs baseline: 2.0497x; 2.0497x over previous
//
#include <hip/hip_runtime.h>

// ---------------------------------------------------------------------------
// DecoderLayer forward: B=4, S=2048, D=1024, F=4096, single-head causal attn.
// Round 12 = round 10 (best: 524us) + two safe memory cuts:
//   (a) scores GEMM outputs bf16 (halves score write; softmax reads bf16),
//   (b) softmax writes only k < ceil((q+1)/128)*128 (PV's CAUSAL_KLIM never
//       reads beyond; saves ~16MB of zero-fill writes).
// GEMM: 128x128 tile, dbuf LDS, 1 barrier/iter, global_load_lds width=16,
// XOR-swizzle (0 conflicts), super-tile remap, normal operand order.
// r11 lesson: buffer_load->VGPR->ds_write staging spills (scratch storm,
// 2x memory traffic, 11% MfmaUtil) — DMA staging is the source-level optimum.
// ---------------------------------------------------------------------------

typedef __attribute__((ext_vector_type(8))) short short8;   // 8 x bf16 (4 VGPR)
typedef __attribute__((ext_vector_type(4))) float f32x4;    // MFMA C/D

#define DMODEL 1024
#define DFF    4096
#define NB     4
#define SEQ    2048
#define NROWS  (NB * SEQ)   // 8192
#define QKVN   (3 * DMODEL) // 3072

__device__ __forceinline__ unsigned short f2bf(float f) {
  union { float f; unsigned u; } v; v.f = f;
  unsigned r = v.u + 0x7FFFu + ((v.u >> 16) & 1u);  // round-to-nearest-even
  return (unsigned short)(r >> 16);
}
__device__ __forceinline__ float bf2f(unsigned short h) {
  union { unsigned u; float f; } v; v.u = ((unsigned)h) << 16;
  return v.f;
}

// async global -> LDS, 16 bytes per lane; lds base must be wave-uniform,
// lane i's data lands at lds + i*16 (m104/m108 constraint).
__device__ __forceinline__ void g2l16(const unsigned short* g, unsigned short* lds) {
  __builtin_amdgcn_global_load_lds(
      (const __attribute__((address_space(1))) void*)g,
      (__attribute__((address_space(3))) void*)lds,
      16, 0, 0);
}

// ---- fp32 -> bf16 convert, all 6 weight tensors in one launch ----
__global__ __launch_bounds__(256) void cvt_bf16_all(
    const float* __restrict__ s0, const float* __restrict__ s1,
    const float* __restrict__ s2, const float* __restrict__ s3,
    const float* __restrict__ s4, const float* __restrict__ s5,
    unsigned short* __restrict__ d0, unsigned short* __restrict__ d1,
    unsigned short* __restrict__ d2, unsigned short* __restrict__ d3,
    unsigned short* __restrict__ d4, unsigned short* __restrict__ d5,
    int n_small, int n_big) {
  const int z = blockIdx.y;
  const float* src; unsigned short* dst; int n4;
  switch (z) {
    case 0: src = s0; dst = d0; n4 = n_small; break;
    case 1: src = s1; dst = d1; n4 = n_small; break;
    case 2: src = s2; dst = d2; n4 = n_small; break;
    case 3: src = s3; dst = d3; n4 = n_small; break;
    case 4: src = s4; dst = d4; n4 = n_big;   break;
    default: src = s5; dst = d5; n4 = n_big;  break;
  }
  int i = blockIdx.x * 256 + threadIdx.x;
  if (i >= n4) return;
  float4 v = reinterpret_cast<const float4*>(src)[i];
  ushort4 o;
  o.x = f2bf(v.x); o.y = f2bf(v.y); o.z = f2bf(v.z); o.w = f2bf(v.w);
  reinterpret_cast<ushort4*>(dst)[i] = o;
}

// ---- LayerNorm over D=1024, one 256-thread block per row, bf16 out ----
__global__ __launch_bounds__(256) void ln_bf16(const float* __restrict__ x,
                                               const float* __restrict__ g,
                                               const float* __restrict__ b,
                                               unsigned short* __restrict__ out) {
  int row = blockIdx.x;
  int t = threadIdx.x;
  const float* xr = x + (size_t)row * DMODEL;
  float4 v = reinterpret_cast<const float4*>(xr)[t];
  float s  = v.x + v.y + v.z + v.w;
  float s2 = v.x*v.x + v.y*v.y + v.z*v.z + v.w*v.w;
  #pragma unroll
  for (int off = 32; off > 0; off >>= 1) {
    s  += __shfl_down(s, off);
    s2 += __shfl_down(s2, off);
  }
  __shared__ float rs[4], rs2[4], stats[2];
  int lane = t & 63, wave = t >> 6;
  if (lane == 0) { rs[wave] = s; rs2[wave] = s2; }
  __syncthreads();
  if (t == 0) {
    float ts  = rs[0] + rs[1] + rs[2] + rs[3];
    float ts2 = rs2[0] + rs2[1] + rs2[2] + rs2[3];
    float mu = ts / DMODEL;
    stats[0] = mu;
    stats[1] = rsqrtf(ts2 / DMODEL - mu * mu + 1e-5f);
  }
  __syncthreads();
  float mu = stats[0], rstd = stats[1];
  float4 gg = reinterpret_cast<const float4*>(g)[t];
  float4 bb = reinterpret_cast<const float4*>(b)[t];
  ushort4 o;
  o.x = f2bf((v.x - mu) * rstd * gg.x + bb.x);
  o.y = f2bf((v.y - mu) * rstd * gg.y + bb.y);
  o.z = f2bf((v.z - mu) * rstd * gg.z + bb.z);
  o.w = f2bf((v.w - mu) * rstd * gg.w + bb.w);
  reinterpret_cast<ushort4*>(out + (size_t)row * DMODEL)[t] = o;
}

// ---- bf16 tile transpose: in [R][C] (row stride ldin) -> out [C][R] ----
__global__ __launch_bounds__(256) void transpose_bf16(const unsigned short* __restrict__ in,
                                                      unsigned short* __restrict__ out,
                                                      int R, int C, int ldin,
                                                      size_t sIn, size_t sOut) {
  __shared__ unsigned short tile[32][33];
  in  += (size_t)blockIdx.z * sIn;
  out += (size_t)blockIdx.z * sOut;
  int c0 = blockIdx.x * 32, r0 = blockIdx.y * 32;
  int tx = threadIdx.x & 31, ty = threadIdx.x >> 5;  // 32 x 8
  #pragma unroll
  for (int i = 0; i < 4; ++i)
    tile[ty + i * 8][tx] = in[(size_t)(r0 + ty + i * 8) * ldin + c0 + tx];
  __syncthreads();
  #pragma unroll
  for (int i = 0; i < 4; ++i)
    out[(size_t)(c0 + ty + i * 8) * R + r0 + tx] = tile[tx][ty + i * 8];
}

// ---- causal row softmax: bf16 scores -> bf16 probs; writes only the
// k-range PV will read (k < ceil((q+1)/128)*128) ----
__global__ __launch_bounds__(256) void softmax_causal(const unsigned short* __restrict__ Sc,
                                                      unsigned short* __restrict__ P) {
  const int q = blockIdx.x, b = blockIdx.y;
  const unsigned short* srow = Sc + ((size_t)b * SEQ + q) * SEQ;
  unsigned short* prow = P + ((size_t)b * SEQ + q) * SEQ;
  const int L = q + 1;
  const int kcap = (q & ~127) + 128;   // PV reads k < m0+128 = kcap for row q
  const int t = threadIdx.x;
  __shared__ float red[4];
  __shared__ float bc;

  float mx = -1e30f;
  for (int i = t; i < L; i += 256) mx = fmaxf(mx, bf2f(srow[i]));
  #pragma unroll
  for (int off = 32; off > 0; off >>= 1) mx = fmaxf(mx, __shfl_down(mx, off));
  if ((t & 63) == 0) red[t >> 6] = mx;
  __syncthreads();
  if (t == 0) bc = fmaxf(fmaxf(red[0], red[1]), fmaxf(red[2], red[3]));
  __syncthreads();
  mx = bc;

  float sum = 0.f;
  for (int i = t; i < L; i += 256) sum += __expf(bf2f(srow[i]) - mx);
  #pragma unroll
  for (int off = 32; off > 0; off >>= 1) sum += __shfl_down(sum, off);
  __syncthreads();            // red reuse guard
  if ((t & 63) == 0) red[t >> 6] = sum;
  __syncthreads();
  if (t == 0) bc = 1.0f / (red[0] + red[1] + red[2] + red[3]);
  __syncthreads();
  float inv = bc;

  for (int i = t; i < kcap; i += 256) {
    float p = (i < L) ? __expf(bf2f(srow[i]) - mx) * inv : 0.f;
    prow[i] = f2bf(p);
  }
}

// ---------------------------------------------------------------------------
// bf16 MFMA GEMM:  C[M,N] = A[M,K] * B[N,K]^T   (both K-contiguous)
// 128x128 tile, 4 waves (2x2), 4x4 of 16x16x32 MFMA, BK=64, dbuf LDS,
// ONE barrier/iter, global_load_lds width=16 staging, XOR-swizzle (0 bank
// conflicts both sides), 8x8 super-tile remap. Normal operand order.
// Epilogue fuses: scale, bias, relu, fp32-residual-add; fp32 or bf16 out.
// ---------------------------------------------------------------------------
template<bool OUT_F32, bool ADD_BIAS, bool RELU, bool ADD_RESID,
         bool CAUSAL_SKIP, bool CAUSAL_KLIM, bool SCALE>
__global__ __launch_bounds__(256) void gemm_bt(
    const unsigned short* __restrict__ A, size_t sA,
    const unsigned short* __restrict__ B, size_t sB,
    void* __restrict__ Cv, size_t sC,
    const float* __restrict__ bias,
    const float* __restrict__ resid, size_t sR,
    int K, int lda, int ldb, int ldc, float scale) {
  // ---- super-tile remap: 64 consecutive linear ids = 8 m-blocks x 8 n-blocks
  const int GX = gridDim.x;                    // m-blocks (multiple of 8)
  const int linear = blockIdx.y * GX + blockIdx.x;
  const int tileId = linear >> 6;
  const int within = linear & 63;
  const int mGroups = GX >> 3;
  const int m_blk = (tileId % mGroups) * 8 + (within & 7);
  const int n_blk = (tileId / mGroups) * 8 + (within >> 3);
  const int m0 = m_blk * 128;
  const int n0 = n_blk * 128;
  if (CAUSAL_SKIP && n0 > m0 + 127) return;  // block fully masked
  const int bz = blockIdx.z;
  A += (size_t)bz * sA;
  B += (size_t)bz * sB;

  __shared__ unsigned short As[2][128 * 64];   // 2 x 16 KB, XOR-swizzled
  __shared__ unsigned short Bs[2][128 * 64];

  const int t = threadIdx.x;
  const int lane = t & 63;
  const int wave = t >> 6;
  const int wm = (wave >> 1) * 64;
  const int wn = (wave & 1) * 64;
  const int lr = lane & 15;
  const int lq = lane >> 4;

  const int srow = lane >> 3;                  // 0..7
  const int pcol = ((lane & 7) ^ srow) * 8;    // XOR-swizzled fetch col

  f32x4 acc[4][4] = {};

  const int kEnd  = CAUSAL_KLIM ? min(K, m0 + 128) : K;
  const int nIter = kEnd >> 6;                 // BK = 64

  auto stage = [&](int buf, int kt) {
    #pragma unroll
    for (int i = 0; i < 4; ++i) {
      const int c = wave * 4 + i;              // chunk 0..15
      const int row = c * 8 + srow;
      g2l16(&A[(size_t)(m0 + row) * lda + kt + pcol], &As[buf][c * 512]);
      g2l16(&B[(size_t)(n0 + row) * ldb + kt + pcol], &Bs[buf][c * 512]);
    }
  };

  stage(0, 0);

  for (int it = 0; it < nIter; ++it) {
    __syncthreads();   // drains vmcnt: buf[it&1] ready; other free to fill
    if (it + 1 < nIter) stage((it + 1) & 1, (it + 1) << 6);
    const unsigned short* Ab = As[it & 1];
    const unsigned short* Bb = Bs[it & 1];
    #pragma unroll
    for (int kk = 0; kk < 2; ++kk) {
      short8 af[4], bfr[4];
      #pragma unroll
      for (int i = 0; i < 4; ++i) {
        const int r = wm + i * 16 + lr;
        af[i] = *reinterpret_cast<const short8*>(
            &Ab[r * 64 + (((kk * 4 + lq) ^ (r & 7)) * 8)]);
      }
      #pragma unroll
      for (int j = 0; j < 4; ++j) {
        const int r = wn + j * 16 + lr;
        bfr[j] = *reinterpret_cast<const short8*>(
            &Bb[r * 64 + (((kk * 4 + lq) ^ (r & 7)) * 8)]);
      }
      #pragma unroll
      for (int i = 0; i < 4; ++i)
        #pragma unroll
        for (int j = 0; j < 4; ++j)
          acc[i][j] = __builtin_amdgcn_mfma_f32_16x16x32_bf16(af[i], bfr[j], acc[i][j], 0, 0, 0);
    }
  }

  float* Cf = (float*)Cv + (size_t)bz * sC;
  unsigned short* Ch = (unsigned short*)Cv + (size_t)bz * sC;
  const float* rr = ADD_RESID ? (resid + (size_t)bz * sR) : nullptr;
  #pragma unroll
  for (int i = 0; i < 4; ++i) {
    #pragma unroll
    for (int j = 0; j < 4; ++j) {
      #pragma unroll
      for (int r = 0; r < 4; ++r) {
        // C/D layout (verified m89/m91): col = lane&15, row = (lane>>4)*4 + reg
        int row = m0 + wm + i * 16 + lq * 4 + r;
        int col = n0 + wn + j * 16 + lr;
        float v = acc[i][j][r];
        if (SCALE)     v *= scale;
        if (ADD_BIAS)  v += bias[col];
        if (RELU)      v = fmaxf(v, 0.0f);
        if (ADD_RESID) v += rr[(size_t)row * ldc + col];
        if (OUT_F32) Cf[(size_t)row * ldc + col] = v;
        else         Ch[(size_t)row * ldc + col] = f2bf(v);
      }
    }
  }
}

// ---------------------------------------------------------------------------
extern "C" void kernel_launch(void* const* d_in, const int* in_sizes, int n_in,
                              void* d_out, int out_size, void* d_ws, size_t ws_size,
                              hipStream_t stream) {
  const float* x    = (const float*)d_in[0];
  const float* Wq   = (const float*)d_in[1];
  const float* Wk   = (const float*)d_in[2];
  const float* Wv   = (const float*)d_in[3];
  const float* Wo   = (const float*)d_in[4];
  const float* fc1w = (const float*)d_in[5];
  const float* fc1b = (const float*)d_in[6];
  const float* fc2w = (const float*)d_in[7];
  const float* fc2b = (const float*)d_in[8];
  const float* ln1g = (const float*)d_in[9];
  const float* ln1b = (const float*)d_in[10];
  const float* ln2g = (const float*)d_in[11];
  const float* ln2b = (const float*)d_in[12];
  float* out = (float*)d_out;

  // workspace carve-up with liveness aliasing
  char* w = (char*)d_ws;
  auto alloc = [&](size_t bytes) {
    char* p = w;
    w += (bytes + 255) & ~(size_t)255;
    return p;
  };
  typedef unsigned short u16;
  u16* wqkv_b = (u16*)alloc((size_t)QKVN * DMODEL * 2);   // stacked Q|K|V
  u16* wq_b   = wqkv_b;
  u16* wk_b   = wqkv_b + (size_t)DMODEL * DMODEL;
  u16* wv_b   = wqkv_b + (size_t)2 * DMODEL * DMODEL;
  u16* wo_b   = (u16*)alloc((size_t)DMODEL * DMODEL * 2);
  u16* fc1w_b = (u16*)alloc((size_t)DFF * DMODEL * 2);
  u16* fc2w_b = (u16*)alloc((size_t)DMODEL * DFF * 2);
  u16* xn     = (u16*)alloc((size_t)NROWS * DMODEL * 2);
  u16* qkv    = (u16*)alloc((size_t)NROWS * QKVN * 2);    // 48 MB
  u16* vt     = (u16*)alloc((size_t)NROWS * DMODEL * 2);
  u16* ctx    = (u16*)alloc((size_t)NROWS * DMODEL * 2);
  u16* xn2    = (u16*)alloc((size_t)NROWS * DMODEL * 2);
  // Region A (64 MB): sc_h (bf16 scores, steps 5-6) aliased with hbuf (10-11)
  char* regA  = (char*)alloc((size_t)NB * SEQ * SEQ * 4);
  u16*   sc_h = (u16*)regA;
  u16*   hbuf = (u16*)regA;
  // Region B (32 MB): Pbuf (steps 6-7) aliased with x1 (steps 8-11)
  char* regB  = (char*)alloc((size_t)NB * SEQ * SEQ * 2);
  u16*   Pbuf = (u16*)regB;
  float* x1   = (float*)regB;

  // 1. weights -> bf16 (single launch; z selects tensor)
  {
    int n_small = DMODEL * DMODEL / 4;
    int n_big   = DFF * DMODEL / 4;
    dim3 g((n_big + 255) / 256, 6);
    cvt_bf16_all<<<g, 256, 0, stream>>>(Wq, Wk, Wv, Wo, fc1w, fc2w,
                                        wq_b, wk_b, wv_b, wo_b, fc1w_b, fc2w_b,
                                        n_small, n_big);
  }

  // 2. LN1
  ln_bf16<<<dim3(NROWS), 256, 0, stream>>>(x, ln1g, ln1b, xn);

  // 3. merged QKV projection: [8192,1024] x [3072,1024]^T -> qkv [8192,3072]
  {
    dim3 g(NROWS / 128, QKVN / 128, 1);
    gemm_bt<false,false,false,false,false,false,false><<<g, 256, 0, stream>>>(
        xn, 0, wqkv_b, 0, qkv, 0, nullptr, nullptr, 0,
        DMODEL, DMODEL, DMODEL, QKVN, 1.f);
  }
  const u16* qb = qkv;                 // lda = QKVN
  const u16* kb = qkv + DMODEL;
  const u16* vb = qkv + 2 * DMODEL;

  // 4. V^T per batch: [2048,1024] (stride 3072) -> [1024,2048]
  transpose_bf16<<<dim3(DMODEL / 32, SEQ / 32, NB), 256, 0, stream>>>(
      vb, vt, SEQ, DMODEL, QKVN, (size_t)SEQ * QKVN, (size_t)DMODEL * SEQ);

  // 5. scores = Q K^T / sqrt(D), bf16 out, skip fully-masked blocks
  {
    dim3 g(SEQ / 128, SEQ / 128, NB);
    gemm_bt<false,false,false,false,true,false,true><<<g, 256, 0, stream>>>(
        qb, (size_t)SEQ * QKVN, kb, (size_t)SEQ * QKVN, sc_h, (size_t)SEQ * SEQ,
        nullptr, nullptr, 0, DMODEL, QKVN, QKVN, SEQ, 0.03125f /*1/sqrt(1024)*/);
  }

  // 6. causal softmax (bf16 in/out; writes only k < ceil((q+1)/128)*128)
  softmax_causal<<<dim3(SEQ, NB), 256, 0, stream>>>(sc_h, Pbuf);

  // 7. ctx = P V  (K-reduction bounded by causality)
  {
    dim3 g(SEQ / 128, DMODEL / 128, NB);
    gemm_bt<false,false,false,false,false,true,false><<<g, 256, 0, stream>>>(
        Pbuf, (size_t)SEQ * SEQ, vt, (size_t)DMODEL * SEQ, ctx, (size_t)SEQ * DMODEL,
        nullptr, nullptr, 0, SEQ, SEQ, SEQ, DMODEL, 1.f);
  }

  // 8. x1 = x + ctx Wo^T  (fp32)  -- x1 aliases Pbuf (dead after step 7)
  {
    dim3 g(NROWS / 128, DMODEL / 128, 1);
    gemm_bt<true,false,false,true,false,false,false><<<g, 256, 0, stream>>>(
        ctx, 0, wo_b, 0, x1, 0, nullptr, x, 0, DMODEL, DMODEL, DMODEL, DMODEL, 1.f);
  }

  // 9. LN2
  ln_bf16<<<dim3(NROWS), 256, 0, stream>>>(x1, ln2g, ln2b, xn2);

  // 10. h = relu(xn2 fc1_w^T + fc1_b)  bf16 [8192,4096] -- hbuf aliases sc_h
  {
    dim3 g(NROWS / 128, DFF / 128, 1);
    gemm_bt<false,true,true,false,false,false,false><<<g, 256, 0, stream>>>(
        xn2, 0, fc1w_b, 0, hbuf, 0, fc1b, nullptr, 0, DMODEL, DMODEL, DMODEL, DFF, 1.f);
  }

  // 11. out = x1 + h fc2_w^T + fc2_b  (fp32)
  {
    dim3 g(NROWS / 128, DMODEL / 128, 1);
    gemm_bt<true,true,false,true,false,false,false><<<g, 256, 0, stream>>>(
        hbuf, 0, fc2w_b, 0, out, 0, fc2b, x1, 0, DFF, DFF, DFF, DMODEL, 1.f);
  }
}

// Round 13
// 514.816 us; speedup vs baseline: 2.0675x; 1.0087x over previous
//
#include <hip/hip_runtime.h>

// ---------------------------------------------------------------------------
// DecoderLayer forward: B=4, S=2048, D=1024, F=4096, single-head causal attn.
// Round 13 = round 12 (519us) + FC1 moved to a 256x256 single-buffer tile:
//   FLOP/B = BM*BN/(BM+BN) = 128 (2x the 128-tile's 64). 64 KB LDS (the
//   per-WG cap), 1024 thr = 16 waves (4x4 of 64x64), BK=64, 2 barriers/iter,
//   global_load_lds + XOR swizzle. Grid 32x16 = 512 = exactly 2 CU-waves.
// Staging rate is pinned ~17 B/cyc/CU by the DMA path (r3-r11 evidence), so
// doubling FLOP/B is the only remaining lever on the big GEMMs.
// FC2/Wo/QKV keep the 128x128 dbuf kernel (grid under-fill / quantization).
// ---------------------------------------------------------------------------

typedef __attribute__((ext_vector_type(8))) short short8;   // 8 x bf16 (4 VGPR)
typedef __attribute__((ext_vector_type(4))) float f32x4;    // MFMA C/D

#define DMODEL 1024
#define DFF    4096
#define NB     4
#define SEQ    2048
#define NROWS  (NB * SEQ)   // 8192
#define QKVN   (3 * DMODEL) // 3072

__device__ __forceinline__ unsigned short f2bf(float f) {
  union { float f; unsigned u; } v; v.f = f;
  unsigned r = v.u + 0x7FFFu + ((v.u >> 16) & 1u);  // round-to-nearest-even
  return (unsigned short)(r >> 16);
}
__device__ __forceinline__ float bf2f(unsigned short h) {
  union { unsigned u; float f; } v; v.u = ((unsigned)h) << 16;
  return v.f;
}

// async global -> LDS, 16 bytes per lane; lds base must be wave-uniform,
// lane i's data lands at lds + i*16 (m104/m108 constraint).
__device__ __forceinline__ void g2l16(const unsigned short* g, unsigned short* lds) {
  __builtin_amdgcn_global_load_lds(
      (const __attribute__((address_space(1))) void*)g,
      (__attribute__((address_space(3))) void*)lds,
      16, 0, 0);
}

// ---- fp32 -> bf16 convert, all 6 weight tensors in one launch ----
__global__ __launch_bounds__(256) void cvt_bf16_all(
    const float* __restrict__ s0, const float* __restrict__ s1,
    const float* __restrict__ s2, const float* __restrict__ s3,
    const float* __restrict__ s4, const float* __restrict__ s5,
    unsigned short* __restrict__ d0, unsigned short* __restrict__ d1,
    unsigned short* __restrict__ d2, unsigned short* __restrict__ d3,
    unsigned short* __restrict__ d4, unsigned short* __restrict__ d5,
    int n_small, int n_big) {
  const int z = blockIdx.y;
  const float* src; unsigned short* dst; int n4;
  switch (z) {
    case 0: src = s0; dst = d0; n4 = n_small; break;
    case 1: src = s1; dst = d1; n4 = n_small; break;
    case 2: src = s2; dst = d2; n4 = n_small; break;
    case 3: src = s3; dst = d3; n4 = n_small; break;
    case 4: src = s4; dst = d4; n4 = n_big;   break;
    default: src = s5; dst = d5; n4 = n_big;  break;
  }
  int i = blockIdx.x * 256 + threadIdx.x;
  if (i >= n4) return;
  float4 v = reinterpret_cast<const float4*>(src)[i];
  ushort4 o;
  o.x = f2bf(v.x); o.y = f2bf(v.y); o.z = f2bf(v.z); o.w = f2bf(v.w);
  reinterpret_cast<ushort4*>(dst)[i] = o;
}

// ---- LayerNorm over D=1024, one 256-thread block per row, bf16 out ----
__global__ __launch_bounds__(256) void ln_bf16(const float* __restrict__ x,
                                               const float* __restrict__ g,
                                               const float* __restrict__ b,
                                               unsigned short* __restrict__ out) {
  int row = blockIdx.x;
  int t = threadIdx.x;
  const float* xr = x + (size_t)row * DMODEL;
  float4 v = reinterpret_cast<const float4*>(xr)[t];
  float s  = v.x + v.y + v.z + v.w;
  float s2 = v.x*v.x + v.y*v.y + v.z*v.z + v.w*v.w;
  #pragma unroll
  for (int off = 32; off > 0; off >>= 1) {
    s  += __shfl_down(s, off);
    s2 += __shfl_down(s2, off);
  }
  __shared__ float rs[4], rs2[4], stats[2];
  int lane = t & 63, wave = t >> 6;
  if (lane == 0) { rs[wave] = s; rs2[wave] = s2; }
  __syncthreads();
  if (t == 0) {
    float ts  = rs[0] + rs[1] + rs[2] + rs[3];
    float ts2 = rs2[0] + rs2[1] + rs2[2] + rs2[3];
    float mu = ts / DMODEL;
    stats[0] = mu;
    stats[1] = rsqrtf(ts2 / DMODEL - mu * mu + 1e-5f);
  }
  __syncthreads();
  float mu = stats[0], rstd = stats[1];
  float4 gg = reinterpret_cast<const float4*>(g)[t];
  float4 bb = reinterpret_cast<const float4*>(b)[t];
  ushort4 o;
  o.x = f2bf((v.x - mu) * rstd * gg.x + bb.x);
  o.y = f2bf((v.y - mu) * rstd * gg.y + bb.y);
  o.z = f2bf((v.z - mu) * rstd * gg.z + bb.z);
  o.w = f2bf((v.w - mu) * rstd * gg.w + bb.w);
  reinterpret_cast<ushort4*>(out + (size_t)row * DMODEL)[t] = o;
}

// ---- bf16 tile transpose: in [R][C] (row stride ldin) -> out [C][R] ----
__global__ __launch_bounds__(256) void transpose_bf16(const unsigned short* __restrict__ in,
                                                      unsigned short* __restrict__ out,
                                                      int R, int C, int ldin,
                                                      size_t sIn, size_t sOut) {
  __shared__ unsigned short tile[32][33];
  in  += (size_t)blockIdx.z * sIn;
  out += (size_t)blockIdx.z * sOut;
  int c0 = blockIdx.x * 32, r0 = blockIdx.y * 32;
  int tx = threadIdx.x & 31, ty = threadIdx.x >> 5;  // 32 x 8
  #pragma unroll
  for (int i = 0; i < 4; ++i)
    tile[ty + i * 8][tx] = in[(size_t)(r0 + ty + i * 8) * ldin + c0 + tx];
  __syncthreads();
  #pragma unroll
  for (int i = 0; i < 4; ++i)
    out[(size_t)(c0 + ty + i * 8) * R + r0 + tx] = tile[tx][ty + i * 8];
}

// ---- causal row softmax: bf16 scores -> bf16 probs; writes only the
// k-range PV will read (k < ceil((q+1)/128)*128) ----
__global__ __launch_bounds__(256) void softmax_causal(const unsigned short* __restrict__ Sc,
                                                      unsigned short* __restrict__ P) {
  const int q = blockIdx.x, b = blockIdx.y;
  const unsigned short* srow = Sc + ((size_t)b * SEQ + q) * SEQ;
  unsigned short* prow = P + ((size_t)b * SEQ + q) * SEQ;
  const int L = q + 1;
  const int kcap = (q & ~127) + 128;   // PV reads k < m0+128 = kcap for row q
  const int t = threadIdx.x;
  __shared__ float red[4];
  __shared__ float bc;

  float mx = -1e30f;
  for (int i = t; i < L; i += 256) mx = fmaxf(mx, bf2f(srow[i]));
  #pragma unroll
  for (int off = 32; off > 0; off >>= 1) mx = fmaxf(mx, __shfl_down(mx, off));
  if ((t & 63) == 0) red[t >> 6] = mx;
  __syncthreads();
  if (t == 0) bc = fmaxf(fmaxf(red[0], red[1]), fmaxf(red[2], red[3]));
  __syncthreads();
  mx = bc;

  float sum = 0.f;
  for (int i = t; i < L; i += 256) sum += __expf(bf2f(srow[i]) - mx);
  #pragma unroll
  for (int off = 32; off > 0; off >>= 1) sum += __shfl_down(sum, off);
  __syncthreads();            // red reuse guard
  if ((t & 63) == 0) red[t >> 6] = sum;
  __syncthreads();
  if (t == 0) bc = 1.0f / (red[0] + red[1] + red[2] + red[3]);
  __syncthreads();
  float inv = bc;

  for (int i = t; i < kcap; i += 256) {
    float p = (i < L) ? __expf(bf2f(srow[i]) - mx) * inv : 0.f;
    prow[i] = f2bf(p);
  }
}

// ---------------------------------------------------------------------------
// 128x128 GEMM (QKV / scores / PV / Wo / FC2): 4 waves (2x2 of 64x64), BK=64,
// dbuf LDS, 1 barrier/iter, global_load_lds width=16, XOR swizzle (0 bank
// conflicts), 8x8 super-tile remap. (round-12 kernel, unchanged)
// ---------------------------------------------------------------------------
template<bool OUT_F32, bool ADD_BIAS, bool RELU, bool ADD_RESID,
         bool CAUSAL_SKIP, bool CAUSAL_KLIM, bool SCALE>
__global__ __launch_bounds__(256) void gemm_bt(
    const unsigned short* __restrict__ A, size_t sA,
    const unsigned short* __restrict__ B, size_t sB,
    void* __restrict__ Cv, size_t sC,
    const float* __restrict__ bias,
    const float* __restrict__ resid, size_t sR,
    int K, int lda, int ldb, int ldc, float scale) {
  const int GX = gridDim.x;                    // m-blocks (multiple of 8)
  const int linear = blockIdx.y * GX + blockIdx.x;
  const int tileId = linear >> 6;
  const int within = linear & 63;
  const int mGroups = GX >> 3;
  const int m_blk = (tileId % mGroups) * 8 + (within & 7);
  const int n_blk = (tileId / mGroups) * 8 + (within >> 3);
  const int m0 = m_blk * 128;
  const int n0 = n_blk * 128;
  if (CAUSAL_SKIP && n0 > m0 + 127) return;  // block fully masked
  const int bz = blockIdx.z;
  A += (size_t)bz * sA;
  B += (size_t)bz * sB;

  __shared__ unsigned short As[2][128 * 64];   // 2 x 16 KB, XOR-swizzled
  __shared__ unsigned short Bs[2][128 * 64];

  const int t = threadIdx.x;
  const int lane = t & 63;
  const int wave = t >> 6;
  const int wm = (wave >> 1) * 64;
  const int wn = (wave & 1) * 64;
  const int lr = lane & 15;
  const int lq = lane >> 4;

  const int srow = lane >> 3;                  // 0..7
  const int pcol = ((lane & 7) ^ srow) * 8;    // XOR-swizzled fetch col

  f32x4 acc[4][4] = {};

  const int kEnd  = CAUSAL_KLIM ? min(K, m0 + 128) : K;
  const int nIter = kEnd >> 6;                 // BK = 64

  auto stage = [&](int buf, int kt) {
    #pragma unroll
    for (int i = 0; i < 4; ++i) {
      const int c = wave * 4 + i;              // chunk 0..15
      const int row = c * 8 + srow;
      g2l16(&A[(size_t)(m0 + row) * lda + kt + pcol], &As[buf][c * 512]);
      g2l16(&B[(size_t)(n0 + row) * ldb + kt + pcol], &Bs[buf][c * 512]);
    }
  };

  stage(0, 0);

  for (int it = 0; it < nIter; ++it) {
    __syncthreads();   // drains vmcnt: buf[it&1] ready; other free to fill
    if (it + 1 < nIter) stage((it + 1) & 1, (it + 1) << 6);
    const unsigned short* Ab = As[it & 1];
    const unsigned short* Bb = Bs[it & 1];
    #pragma unroll
    for (int kk = 0; kk < 2; ++kk) {
      short8 af[4], bfr[4];
      #pragma unroll
      for (int i = 0; i < 4; ++i) {
        const int r = wm + i * 16 + lr;
        af[i] = *reinterpret_cast<const short8*>(
            &Ab[r * 64 + (((kk * 4 + lq) ^ (r & 7)) * 8)]);
      }
      #pragma unroll
      for (int j = 0; j < 4; ++j) {
        const int r = wn + j * 16 + lr;
        bfr[j] = *reinterpret_cast<const short8*>(
            &Bb[r * 64 + (((kk * 4 + lq) ^ (r & 7)) * 8)]);
      }
      #pragma unroll
      for (int i = 0; i < 4; ++i)
        #pragma unroll
        for (int j = 0; j < 4; ++j)
          acc[i][j] = __builtin_amdgcn_mfma_f32_16x16x32_bf16(af[i], bfr[j], acc[i][j], 0, 0, 0);
    }
  }

  float* Cf = (float*)Cv + (size_t)bz * sC;
  unsigned short* Ch = (unsigned short*)Cv + (size_t)bz * sC;
  const float* rr = ADD_RESID ? (resid + (size_t)bz * sR) : nullptr;
  #pragma unroll
  for (int i = 0; i < 4; ++i) {
    #pragma unroll
    for (int j = 0; j < 4; ++j) {
      #pragma unroll
      for (int r = 0; r < 4; ++r) {
        // C/D layout (verified m89/m91): col = lane&15, row = (lane>>4)*4 + reg
        int row = m0 + wm + i * 16 + lq * 4 + r;
        int col = n0 + wn + j * 16 + lr;
        float v = acc[i][j][r];
        if (SCALE)     v *= scale;
        if (ADD_BIAS)  v += bias[col];
        if (RELU)      v = fmaxf(v, 0.0f);
        if (ADD_RESID) v += rr[(size_t)row * ldc + col];
        if (OUT_F32) Cf[(size_t)row * ldc + col] = v;
        else         Ch[(size_t)row * ldc + col] = f2bf(v);
      }
    }
  }
}

// ---------------------------------------------------------------------------
// 256x256 GEMM (FC1): 1024 threads = 16 waves (4x4 of 64x64), BK=64,
// SINGLE-buffer 64 KB LDS (per-WG cap), 2 barriers/iter, global_load_lds +
// XOR swizzle. FLOP/B = 128 (2x the 128-tile). 64 chunks / 16 waves = 4 DMA
// per wave per iter. Epilogue fuses bias+relu; bf16 out.
// ---------------------------------------------------------------------------
template<bool OUT_F32, bool ADD_BIAS, bool RELU>
__global__ __launch_bounds__(1024) void gemm_bt256(
    const unsigned short* __restrict__ A,
    const unsigned short* __restrict__ B,
    void* __restrict__ Cv,
    const float* __restrict__ bias,
    int K, int lda, int ldb, int ldc) {
  const int GX = gridDim.x;                    // m-blocks (multiple of 8)
  const int linear = blockIdx.y * GX + blockIdx.x;
  const int tileId = linear >> 6;
  const int within = linear & 63;
  const int mGroups = GX >> 3;
  const int m_blk = (tileId % mGroups) * 8 + (within & 7);
  const int n_blk = (tileId / mGroups) * 8 + (within >> 3);
  const int m0 = m_blk * 256;
  const int n0 = n_blk * 256;

  __shared__ unsigned short As[256 * 64];      // 32 KB, XOR-swizzled
  __shared__ unsigned short Bs[256 * 64];      // 32 KB

  const int t = threadIdx.x;
  const int lane = t & 63;
  const int wave = t >> 6;                     // 0..15
  const int wm = (wave >> 2) * 64;             // 0,64,128,192
  const int wn = (wave & 3) * 64;              // 0,64,128,192
  const int lr = lane & 15;
  const int lq = lane >> 4;

  const int srow = lane >> 3;                  // 0..7
  const int pcol = ((lane & 7) ^ srow) * 8;    // XOR-swizzled fetch col

  f32x4 acc[4][4] = {};
  const int nIter = K >> 6;                    // BK = 64

  for (int it = 0; it < nIter; ++it) {
    const int kt = it << 6;
    __syncthreads();                           // prev compute done, LDS free
    #pragma unroll
    for (int i = 0; i < 2; ++i) {
      const int c = wave * 2 + i;              // chunk 0..31
      const int row = c * 8 + srow;
      g2l16(&A[(size_t)(m0 + row) * lda + kt + pcol], &As[c * 512]);
      g2l16(&B[(size_t)(n0 + row) * ldb + kt + pcol], &Bs[c * 512]);
    }
    __syncthreads();                           // vmcnt drained before barrier
    #pragma unroll
    for (int kk = 0; kk < 2; ++kk) {
      short8 af[4], bfr[4];
      #pragma unroll
      for (int i = 0; i < 4; ++i) {
        const int r = wm + i * 16 + lr;
        af[i] = *reinterpret_cast<const short8*>(
            &As[r * 64 + (((kk * 4 + lq) ^ (r & 7)) * 8)]);
      }
      #pragma unroll
      for (int j = 0; j < 4; ++j) {
        const int r = wn + j * 16 + lr;
        bfr[j] = *reinterpret_cast<const short8*>(
            &Bs[r * 64 + (((kk * 4 + lq) ^ (r & 7)) * 8)]);
      }
      #pragma unroll
      for (int i = 0; i < 4; ++i)
        #pragma unroll
        for (int j = 0; j < 4; ++j)
          acc[i][j] = __builtin_amdgcn_mfma_f32_16x16x32_bf16(af[i], bfr[j], acc[i][j], 0, 0, 0);
    }
  }

  float* Cf = (float*)Cv;
  unsigned short* Ch = (unsigned short*)Cv;
  #pragma unroll
  for (int i = 0; i < 4; ++i) {
    #pragma unroll
    for (int j = 0; j < 4; ++j) {
      #pragma unroll
      for (int r = 0; r < 4; ++r) {
        int row = m0 + wm + i * 16 + lq * 4 + r;
        int col = n0 + wn + j * 16 + lr;
        float v = acc[i][j][r];
        if (ADD_BIAS) v += bias[col];
        if (RELU)     v = fmaxf(v, 0.0f);
        if (OUT_F32) Cf[(size_t)row * ldc + col] = v;
        else         Ch[(size_t)row * ldc + col] = f2bf(v);
      }
    }
  }
}

// ---------------------------------------------------------------------------
extern "C" void kernel_launch(void* const* d_in, const int* in_sizes, int n_in,
                              void* d_out, int out_size, void* d_ws, size_t ws_size,
                              hipStream_t stream) {
  const float* x    = (const float*)d_in[0];
  const float* Wq   = (const float*)d_in[1];
  const float* Wk   = (const float*)d_in[2];
  const float* Wv   = (const float*)d_in[3];
  const float* Wo   = (const float*)d_in[4];
  const float* fc1w = (const float*)d_in[5];
  const float* fc1b = (const float*)d_in[6];
  const float* fc2w = (const float*)d_in[7];
  const float* fc2b = (const float*)d_in[8];
  const float* ln1g = (const float*)d_in[9];
  const float* ln1b = (const float*)d_in[10];
  const float* ln2g = (const float*)d_in[11];
  const float* ln2b = (const float*)d_in[12];
  float* out = (float*)d_out;

  // workspace carve-up with liveness aliasing
  char* w = (char*)d_ws;
  auto alloc = [&](size_t bytes) {
    char* p = w;
    w += (bytes + 255) & ~(size_t)255;
    return p;
  };
  typedef unsigned short u16;
  u16* wqkv_b = (u16*)alloc((size_t)QKVN * DMODEL * 2);   // stacked Q|K|V
  u16* wq_b   = wqkv_b;
  u16* wk_b   = wqkv_b + (size_t)DMODEL * DMODEL;
  u16* wv_b   = wqkv_b + (size_t)2 * DMODEL * DMODEL;
  u16* wo_b   = (u16*)alloc((size_t)DMODEL * DMODEL * 2);
  u16* fc1w_b = (u16*)alloc((size_t)DFF * DMODEL * 2);
  u16* fc2w_b = (u16*)alloc((size_t)DMODEL * DFF * 2);
  u16* xn     = (u16*)alloc((size_t)NROWS * DMODEL * 2);
  u16* qkv    = (u16*)alloc((size_t)NROWS * QKVN * 2);    // 48 MB
  u16* vt     = (u16*)alloc((size_t)NROWS * DMODEL * 2);
  u16* ctx    = (u16*)alloc((size_t)NROWS * DMODEL * 2);
  u16* xn2    = (u16*)alloc((size_t)NROWS * DMODEL * 2);
  // Region A (64 MB): sc_h (bf16 scores, steps 5-6) aliased with hbuf (10-11)
  char* regA  = (char*)alloc((size_t)NB * SEQ * SEQ * 4);
  u16*   sc_h = (u16*)regA;
  u16*   hbuf = (u16*)regA;
  // Region B (32 MB): Pbuf (steps 6-7) aliased with x1 (steps 8-11)
  char* regB  = (char*)alloc((size_t)NB * SEQ * SEQ * 2);
  u16*   Pbuf = (u16*)regB;
  float* x1   = (float*)regB;

  // 1. weights -> bf16 (single launch; z selects tensor)
  {
    int n_small = DMODEL * DMODEL / 4;
    int n_big   = DFF * DMODEL / 4;
    dim3 g((n_big + 255) / 256, 6);
    cvt_bf16_all<<<g, 256, 0, stream>>>(Wq, Wk, Wv, Wo, fc1w, fc2w,
                                        wq_b, wk_b, wv_b, wo_b, fc1w_b, fc2w_b,
                                        n_small, n_big);
  }

  // 2. LN1
  ln_bf16<<<dim3(NROWS), 256, 0, stream>>>(x, ln1g, ln1b, xn);

  // 3. merged QKV projection: [8192,1024] x [3072,1024]^T -> qkv [8192,3072]
  {
    dim3 g(NROWS / 128, QKVN / 128, 1);
    gemm_bt<false,false,false,false,false,false,false><<<g, 256, 0, stream>>>(
        xn, 0, wqkv_b, 0, qkv, 0, nullptr, nullptr, 0,
        DMODEL, DMODEL, DMODEL, QKVN, 1.f);
  }
  const u16* qb = qkv;                 // lda = QKVN
  const u16* kb = qkv + DMODEL;
  const u16* vb = qkv + 2 * DMODEL;

  // 4. V^T per batch: [2048,1024] (stride 3072) -> [1024,2048]
  transpose_bf16<<<dim3(DMODEL / 32, SEQ / 32, NB), 256, 0, stream>>>(
      vb, vt, SEQ, DMODEL, QKVN, (size_t)SEQ * QKVN, (size_t)DMODEL * SEQ);

  // 5. scores = Q K^T / sqrt(D), bf16 out, skip fully-masked blocks
  {
    dim3 g(SEQ / 128, SEQ / 128, NB);
    gemm_bt<false,false,false,false,true,false,true><<<g, 256, 0, stream>>>(
        qb, (size_t)SEQ * QKVN, kb, (size_t)SEQ * QKVN, sc_h, (size_t)SEQ * SEQ,
        nullptr, nullptr, 0, DMODEL, QKVN, QKVN, SEQ, 0.03125f /*1/sqrt(1024)*/);
  }

  // 6. causal softmax (bf16 in/out; writes only k < ceil((q+1)/128)*128)
  softmax_causal<<<dim3(SEQ, NB), 256, 0, stream>>>(sc_h, Pbuf);

  // 7. ctx = P V  (K-reduction bounded by causality)
  {
    dim3 g(SEQ / 128, DMODEL / 128, NB);
    gemm_bt<false,false,false,false,false,true,false><<<g, 256, 0, stream>>>(
        Pbuf, (size_t)SEQ * SEQ, vt, (size_t)DMODEL * SEQ, ctx, (size_t)SEQ * DMODEL,
        nullptr, nullptr, 0, SEQ, SEQ, SEQ, DMODEL, 1.f);
  }

  // 8. x1 = x + ctx Wo^T  (fp32)  -- x1 aliases Pbuf (dead after step 7)
  {
    dim3 g(NROWS / 128, DMODEL / 128, 1);
    gemm_bt<true,false,false,true,false,false,false><<<g, 256, 0, stream>>>(
        ctx, 0, wo_b, 0, x1, 0, nullptr, x, 0, DMODEL, DMODEL, DMODEL, DMODEL, 1.f);
  }

  // 9. LN2
  ln_bf16<<<dim3(NROWS), 256, 0, stream>>>(x1, ln2g, ln2b, xn2);

  // 10. h = relu(xn2 fc1_w^T + fc1_b)  bf16 [8192,4096]
  //     256x256 tile, grid 32x16 = 512 blocks = exactly 2 CU-waves
  gemm_bt256<false,true,true><<<dim3(NROWS / 256, DFF / 256), 1024, 0, stream>>>(
      xn2, fc1w_b, hbuf, fc1b, DMODEL, DMODEL, DMODEL, DFF);

  // 11. out = x1 + h fc2_w^T + fc2_b  (fp32)
  {
    dim3 g(NROWS / 128, DMODEL / 128, 1);
    gemm_bt<true,true,false,true,false,false,false><<<g, 256, 0, stream>>>(
        hbuf, 0, fc2w_b, 0, out, 0, fc2b, x1, 0, DFF, DFF, DFF, DMODEL, 1.f);
  }
}